// Round 13
// baseline (45.247 us; speedup 1.0000x reference)
//
#include <hip/hip_runtime.h>
#include <math.h>
#include <utility>

static constexpr int HH = 2048;
static constexpr int WW = 2048;
static constexpr int NPIX = HH * WW;
static constexpr int HPR = WW / 16;        // 128 u16 chunks per row
static constexpr int TW = 256;             // tile width  (output)
static constexpr int TH = 64;              // tile height (output)
static constexpr int GX = WW / TW;         // 8
static constexpr int GY = HH / TH;         // 32 -> 256 blocks

// Compile-time-forced loop unrolling (keeps acc[] in registers).
template <typename F, int... Is>
__device__ __forceinline__ void sf_impl(F&& f, std::integer_sequence<int, Is...>) {
    (f(std::integral_constant<int, Is>{}), ...);
}
template <int N, typename F>
__device__ __forceinline__ void static_for(F&& f) {
    sf_impl(f, std::make_integer_sequence<int, N>{});
}

// Rank of squared distance among the 14 distinct d2 values in the 9x9
// neighborhood (ascending). 0 = "no differing neighbor".
__host__ __device__ constexpr int rank_of(int d2) {
    switch (d2) {
        case 1:  return 1;  case 2:  return 2;  case 4:  return 3;
        case 5:  return 4;  case 8:  return 5;  case 9:  return 6;
        case 10: return 7;  case 13: return 8;  case 16: return 9;
        case 17: return 10; case 18: return 11; case 20: return 12;
        case 25: return 13; case 32: return 14;
    }
    return 0;
}

__device__ const int D2S[16] = {0, 1, 2, 4, 5, 8, 9, 10, 13, 16, 17, 18, 20, 25, 32, 0};

// Spread the 8 bits of b into the 8 bytes of a u64 (byte i = (b>>i)&1).
__device__ __forceinline__ unsigned long long spread8(unsigned int b) {
    unsigned long long t = (unsigned long long)b * 0x0101010101010101ull;
    t &= 0x8040201008040201ull;
    return ((t + 0x7f7f7f7f7f7f7f7full) >> 7) & 0x0101010101010101ull;
}

// Fused pack+dist: block owns a 256x64 output tile. Re-reads the 5 masks over
// the clamped 264x72 halo (+16% overfetch), builds bit-tile + fw bytes in LDS
// (ballot-aligned 64-px segments), then runs the u16-grain window dist and
// emits code bytes. R13 fix vs R12: C (center-row window) hoisted BEFORE the
// DY static_for — R12 set it inside at dyi==4, so dy<0 rows XORed against 0.
__global__ __launch_bounds__(512) void k_packdist(const float* __restrict__ t,
                                                  ulonglong2* __restrict__ code16,
                                                  unsigned long long* __restrict__ obs_blk) {
    // pkt: bit c+4 <-> tile col c (c in [-4,260)); row r <-> image row ty0+r-4.
    __shared__ unsigned pkt[TH + 8][9];            // 72 x 9 u32 = 2.6 KB
    __shared__ unsigned char fwt[TH][TW];          // 16 KB
    __shared__ unsigned long long swl[8], swh[8];

    const int bx = blockIdx.x & (GX - 1);
    const int by = blockIdx.x >> 3;                // GX == 8
    const int tx0 = bx * TW, ty0 = by * TH;
    const int wid = threadIdx.x >> 6, lane = threadIdx.x & 63;

    // ---- Pack phase: 360 wave-items = 72 rows x 5 col-segments ----
    // segs 0..3: cols [64s-4, 64s+60) (64 lanes); seg 4: cols [252,260) (8 lanes).
#pragma unroll 5
    for (int it = wid * 45; it < wid * 45 + 45; ++it) {
        const int r = it / 5;
        const int s = it - 5 * r;
        const bool active = (s < 4) | (lane < 8);
        const int c = (s < 4) ? (64 * s - 4 + lane) : (252 + lane);
        const int gy = min(max(ty0 + r - 4, 0), HH - 1);
        const int gx = min(max(tx0 + c, 0), WW - 1);
        float s5 = 0.f;
        if (active) {
            const int o = gy * WW + gx;
            s5 = t[o] + t[NPIX + o] + t[2 * NPIX + o] + t[3 * NPIX + o]
               + t[4 * NPIX + o];
        }
        const unsigned long long bal = __ballot(active && (s5 > 0.f));
        if (lane == 0) {
            if (s < 4) {
                pkt[r][2 * s]     = (unsigned)bal;
                pkt[r][2 * s + 1] = (unsigned)(bal >> 32);
            } else {
                pkt[r][8] = (unsigned)bal;      // bits 0..7 valid, rest 0
            }
        }
        const int rr = r - 4;
        if (active && rr >= 0 && rr < TH && c >= 0 && c < TW)
            fwt[rr][c] = (unsigned char)(int)s5;
    }
    __syncthreads();

    // ---- Dist phase: 1024 chunks (64 rows x 16 u16-chunks), 2 per thread ----
    unsigned long long obl = 0, obh = 0;
#pragma unroll
    for (int k = 0; k < 2; ++k) {
        const int ch = threadIdx.x + k * 512;
        const int rr = ch >> 4;                 // 0..63
        const int cx = ch & 15;
        const int x0 = cx * 16;                 // window start bit = x0
        const int w0 = x0 >> 5;
        const int sh = x0 & 31;                 // 0 or 16

        unsigned acc[15];
        static_for<15>([&](auto I) { acc[I.value] = 0u; });

        // Center-row window, hoisted (R13 fix). W bit b = pkt bit x0+b.
        const unsigned long long Wc =
            ((unsigned long long)pkt[rr + 4][w0]
           | ((unsigned long long)pkt[rr + 4][w0 + 1] << 32)) >> sh;
        const unsigned C = (unsigned)(Wc >> 4);   // bit b = tile col x0+b

        static_for<9>([&](auto DY) {
            constexpr int dyi = DY.value;       // pkt row = rr + dyi
            constexpr int dy = dyi - 4;
            const unsigned long long W = (dyi == 4) ? Wc :
                (((unsigned long long)pkt[rr + dyi][w0]
                | ((unsigned long long)pkt[rr + dyi][w0 + 1] << 32)) >> sh);
            static_for<9>([&](auto DX) {
                constexpr int dx = DX.value - 4;
                if constexpr (!(dx == 0 && dy == 0)) {
                    constexpr int rk = rank_of(dy * dy + dx * dx);
                    const unsigned S = (unsigned)(W >> (4 + dx));
                    acc[rk] |= S ^ C;           // bits >=16 garbage; never read
                }
            });
        });

        // Resolve ascending distance into 4 bitplanes (first-found = min d2).
        unsigned found = 0, p0 = 0, p1 = 0, p2 = 0, p3 = 0;
        static_for<14>([&](auto RI) {
            constexpr int r = RI.value + 1;
            const unsigned nw = acc[r] & ~found;
            found |= acc[r];
            if constexpr (r & 1) p0 |= nw;
            if constexpr (r & 2) p1 |= nw;
            if constexpr (r & 4) p2 |= nw;
            if constexpr (r & 8) p3 |= nw;
        });

        // fw bytes for this chunk (one 16B LDS read).
        const uint4 fvw = *(const uint4*)&fwt[rr][x0];
        const unsigned long long fv0 =
            (unsigned long long)fvw.x | ((unsigned long long)fvw.y << 32);
        const unsigned long long fv1 =
            (unsigned long long)fvw.z | ((unsigned long long)fvw.w << 32);

        unsigned long long cq0 = 0, cq1 = 0;
        static_for<2>([&](auto J) {
            constexpr int j = J.value;
            const unsigned long long f = j ? fv1 : fv0;
            const unsigned c0 = (p0 >> (8 * j)) & 0xff;
            const unsigned c1 = (p1 >> (8 * j)) & 0xff;
            const unsigned c2 = (p2 >> (8 * j)) & 0xff;
            const unsigned c3 = (p3 >> (8 * j)) & 0xff;
            const unsigned long long cls = spread8(c0) | (spread8(c1) << 1)
                                         | (spread8(c2) << 2) | (spread8(c3) << 3);
            const unsigned long long cq = (f << 4) | cls;   // fv<=5, no overflow
            if constexpr (j == 0) cq0 = cq; else cq1 = cq;
            static_for<8>([&](auto B) {
                constexpr int b = B.value;
                const unsigned code = (unsigned)((cq >> (8 * b)) & 0xff);
                const unsigned long long bit = 1ull << (code & 63);
                const bool ishi = (code & 64) != 0;
                obl |= ishi ? 0ull : bit;
                obh |= ishi ? bit : 0ull;
            });
        });
        const int gchunk = (ty0 + rr) * HPR + bx * (TW / 16) + cx;
        code16[gchunk] = make_ulonglong2(cq0, cq1);
    }

    // Wave OR-reduce -> LDS -> single block slot pair (no atomics anywhere).
#pragma unroll
    for (int s = 32; s > 0; s >>= 1) {
        obl |= __shfl_xor(obl, s);
        obh |= __shfl_xor(obh, s);
    }
    if (lane == 0) { swl[wid] = obl; swh[wid] = obh; }
    __syncthreads();
    if (threadIdx.x < 64) {
        unsigned long long l2 = (threadIdx.x < 8) ? swl[threadIdx.x] : 0ull;
        unsigned long long h2 = (threadIdx.x < 8) ? swh[threadIdx.x] : 0ull;
#pragma unroll
        for (int s = 4; s > 0; s >>= 1) {
            l2 |= __shfl_xor(l2, s);
            h2 |= __shfl_xor(h2, s);
        }
        if (threadIdx.x == 0) {
            obs_blk[blockIdx.x * 2]     = l2;
            obs_blk[blockIdx.x * 2 + 1] = h2;
        }
    }
}

// Pass C: OR-reduce 256 per-block obs slots (4 KB), build 96-entry table,
// then 16-px-per-thread LDS-table lookup.
__global__ __launch_bounds__(256) void k_out(const ulonglong2* __restrict__ code16,
                                             const unsigned long long* __restrict__ obs_blk,
                                             float* __restrict__ out) {
    __shared__ float tab[96];
    __shared__ float smn[4], smx[4];
    __shared__ unsigned long long slo[4], shi[4];

    const int tid = threadIdx.x;

    // Preamble: global obs = OR of all 256 block slots (one pair per thread).
    unsigned long long lo, hi;
    {
        const ulonglong2 s = ((const ulonglong2*)obs_blk)[tid];
        lo = s.x;
        hi = s.y;
#pragma unroll
        for (int s2 = 32; s2 > 0; s2 >>= 1) {
            lo |= __shfl_xor(lo, s2);
            hi |= __shfl_xor(hi, s2);
        }
        if ((tid & 63) == 0) { slo[tid >> 6] = lo; shi[tid >> 6] = hi; }
        __syncthreads();
        lo = slo[0] | slo[1] | slo[2] | slo[3];
        hi = shi[0] | shi[1] | shi[2] | shi[3];
    }

    float v = 0.f;
    bool present = false;
    if (tid < 96) {
        const int r = tid & 15;
        const float contour = (r >= 1 && r <= 14) ? 1.f / sqrtf((float)D2S[r]) : 0.f;
        const float t0 = (float)(tid >> 4) + contour;
        v = t0 * t0;
        present = (tid < 64) ? ((lo >> tid) & 1) : ((hi >> (tid - 64)) & 1);
    }
    float mnv = present ? v : INFINITY;
    float mxv = present ? v : -INFINITY;
#pragma unroll
    for (int s = 32; s > 0; s >>= 1) {
        mnv = fminf(mnv, __shfl_xor(mnv, s));
        mxv = fmaxf(mxv, __shfl_xor(mxv, s));
    }
    if ((tid & 63) == 0) { smn[tid >> 6] = mnv; smx[tid >> 6] = mxv; }
    __syncthreads();
    const float mn = fminf(fminf(smn[0], smn[1]), fminf(smn[2], smn[3]));
    const float mx = fmaxf(fmaxf(smx[0], smx[1]), fmaxf(smx[2], smx[3]));
    const float inv = 1.f / (mx - mn + 1e-10f);
    if (tid < 96) tab[tid] = (tid >= 16) ? (v - mn) * inv : 0.f;  // fv==0 -> 0
    __syncthreads();

    // 16 px per thread: one ulonglong2 of codes -> 4 float4 stores.
    const int t = blockIdx.x * 256 + tid;
    const ulonglong2 cq = code16[t];
    float4 v0, v1, v2, v3;
    v0.x = tab[(cq.x >> 0) & 0xff];  v0.y = tab[(cq.x >> 8) & 0xff];
    v0.z = tab[(cq.x >> 16) & 0xff]; v0.w = tab[(cq.x >> 24) & 0xff];
    v1.x = tab[(cq.x >> 32) & 0xff]; v1.y = tab[(cq.x >> 40) & 0xff];
    v1.z = tab[(cq.x >> 48) & 0xff]; v1.w = tab[(cq.x >> 56) & 0xff];
    v2.x = tab[(cq.y >> 0) & 0xff];  v2.y = tab[(cq.y >> 8) & 0xff];
    v2.z = tab[(cq.y >> 16) & 0xff]; v2.w = tab[(cq.y >> 24) & 0xff];
    v3.x = tab[(cq.y >> 32) & 0xff]; v3.y = tab[(cq.y >> 40) & 0xff];
    v3.z = tab[(cq.y >> 48) & 0xff]; v3.w = tab[(cq.y >> 56) & 0xff];
    const int ob = t * 16;
    *(float4*)(out + ob + 0)  = v0;
    *(float4*)(out + ob + 4)  = v1;
    *(float4*)(out + ob + 8)  = v2;
    *(float4*)(out + ob + 12) = v3;
}

extern "C" void kernel_launch(void* const* d_in, const int* in_sizes, int n_in,
                              void* d_out, int out_size, void* d_ws, size_t ws_size,
                              hipStream_t stream) {
    const float* target = (const float*)d_in[0];
    float* out = (float*)d_out;

    // ws layout (16B-aligned): code (NPIX bytes) | obs_blk (256*16 B)
    unsigned char* code = (unsigned char*)d_ws;
    unsigned long long* obs_blk = (unsigned long long*)(code + NPIX);

    k_packdist<<<GX * GY, 512, 0, stream>>>(
        target, (ulonglong2*)code, obs_blk);

    k_out<<<NPIX / 16 / 256, 256, 0, stream>>>(
        (const ulonglong2*)code, obs_blk, out);
}

// Round 14
// 43.402 us; speedup vs baseline: 1.0425x; 1.0425x over previous
//
#include <hip/hip_runtime.h>
#include <math.h>
#include <utility>

static constexpr int HH = 2048;
static constexpr int WW = 2048;
static constexpr int NPIX = HH * WW;
static constexpr int HPR = WW / 16;        // 128 u16 chunks per row (global)
static constexpr int TW = 256;             // tile width  (output)
static constexpr int TH = 64;              // tile height (output)
static constexpr int GX = WW / TW;         // 8
static constexpr int GY = HH / TH;         // 32 -> 256 blocks
static constexpr int NCH = 18;             // halo chunks per row: [tx0-16, tx0+272)
static constexpr int NHR = TH + 8;         // 72 halo rows

// Compile-time-forced loop unrolling (keeps acc[] in registers).
template <typename F, int... Is>
__device__ __forceinline__ void sf_impl(F&& f, std::integer_sequence<int, Is...>) {
    (f(std::integral_constant<int, Is>{}), ...);
}
template <int N, typename F>
__device__ __forceinline__ void static_for(F&& f) {
    sf_impl(f, std::make_integer_sequence<int, N>{});
}

// Rank of squared distance among the 14 distinct d2 values in the 9x9
// neighborhood (ascending). 0 = "no differing neighbor".
__host__ __device__ constexpr int rank_of(int d2) {
    switch (d2) {
        case 1:  return 1;  case 2:  return 2;  case 4:  return 3;
        case 5:  return 4;  case 8:  return 5;  case 9:  return 6;
        case 10: return 7;  case 13: return 8;  case 16: return 9;
        case 17: return 10; case 18: return 11; case 20: return 12;
        case 25: return 13; case 32: return 14;
    }
    return 0;
}

__device__ const int D2S[16] = {0, 1, 2, 4, 5, 8, 9, 10, 13, 16, 17, 18, 20, 25, 32, 0};

// Spread the 8 bits of b into the 8 bytes of a u64 (byte i = (b>>i)&1).
__device__ __forceinline__ unsigned long long spread8(unsigned int b) {
    unsigned long long t = (unsigned long long)b * 0x0101010101010101ull;
    t &= 0x8040201008040201ull;
    return ((t + 0x7f7f7f7f7f7f7f7full) >> 7) & 0x0101010101010101ull;
}

// Fused pack+dist, R14: VECTORIZED pack (16-px chunk items, float4 loads; R13
// was per-pixel scalar -> latency-bound at 19% VALU / 14% HBM) and 1024-thread
// blocks (16 waves/CU, 2x R13's occupancy). Dist = 1 u16 chunk per thread.
__global__ __launch_bounds__(1024, 4) void k_packdist(
        const float* __restrict__ t,
        ulonglong2* __restrict__ code16,
        unsigned long long* __restrict__ obs_blk) {
    __shared__ unsigned short pk16[NHR][NCH];      // bits: 2.6 KB
    __shared__ unsigned char fwt[TH][TW];          // fw bytes: 16 KB
    __shared__ unsigned long long swl[16], swh[16];

    const int bx = blockIdx.x & (GX - 1);
    const int by = blockIdx.x >> 3;                // GX == 8
    const int tx0 = bx * TW, ty0 = by * TH;

    // ---- Pack phase: 1296 chunk-items (72 rows x 18 chunks of 16 px) ----
    for (int it = threadIdx.x; it < NHR * NCH; it += 1024) {
        const int r = it / NCH;                    // 0..71 (magic-mul)
        const int cc = it - r * NCH;               // 0..17
        const int gy = min(max(ty0 + r - 4, 0), HH - 1);
        const int gxb = tx0 - 16 + cc * 16;
        const float* __restrict__ p = t + (size_t)gy * WW + gxb;

        unsigned bits = 0;
        unsigned wq[4];
        if (gxb >= 0 && gxb + 16 <= WW) {          // interior chunk: 20x float4
#pragma unroll
            for (int i = 0; i < 4; ++i) {
                const float4 a = *(const float4*)(p + 4 * i);
                const float4 b = *(const float4*)(p + NPIX + 4 * i);
                const float4 c = *(const float4*)(p + 2 * NPIX + 4 * i);
                const float4 d = *(const float4*)(p + 3 * NPIX + 4 * i);
                const float4 e = *(const float4*)(p + 4 * NPIX + 4 * i);
                const float s0 = a.x + b.x + c.x + d.x + e.x;
                const float s1 = a.y + b.y + c.y + d.y + e.y;
                const float s2 = a.z + b.z + c.z + d.z + e.z;
                const float s3 = a.w + b.w + c.w + d.w + e.w;
                wq[i] = (unsigned)(int)s0 | ((unsigned)(int)s1 << 8)
                      | ((unsigned)(int)s2 << 16) | ((unsigned)(int)s3 << 24);
                bits |= ((s0 > 0.f) ? 1u : 0u) << (4 * i)
                      | ((s1 > 0.f) ? 1u : 0u) << (4 * i + 1)
                      | ((s2 > 0.f) ? 1u : 0u) << (4 * i + 2)
                      | ((s3 > 0.f) ? 1u : 0u) << (4 * i + 3);
            }
        } else {                                   // edge chunk: clamped scalar
#pragma unroll
            for (int i = 0; i < 4; ++i) {
                unsigned w = 0;
#pragma unroll
                for (int j = 0; j < 4; ++j) {
                    const int gx = min(max(gxb + 4 * i + j, 0), WW - 1);
                    const size_t o = (size_t)gy * WW + gx;
                    const float s = t[o] + t[NPIX + o] + t[2 * NPIX + o]
                                  + t[3 * NPIX + o] + t[4 * NPIX + o];
                    w |= ((unsigned)(int)s) << (8 * j);
                    bits |= ((s > 0.f) ? 1u : 0u) << (4 * i + j);
                }
                wq[i] = w;
            }
        }
        pk16[r][cc] = (unsigned short)bits;
        const int rr = r - 4;
        if (rr >= 0 && rr < TH && cc >= 1 && cc <= 16)
            *(uint4*)&fwt[rr][(cc - 1) * 16] = make_uint4(wq[0], wq[1], wq[2], wq[3]);
    }
    __syncthreads();

    // ---- Dist phase: exactly one 16-px chunk per thread (64 rows x 16) ----
    const int rr = threadIdx.x >> 4;               // 0..63
    const int cx = threadIdx.x & 15;               // 0..15
    const int hc = cx + 1;                         // halo chunk of this chunk

    unsigned acc[15];
    static_for<15>([&](auto I) { acc[I.value] = 0u; });

    // Center-row window (hoisted): W bit k = halo col 16*hc - 4 + k.
    const unsigned long long Wc =
        ((unsigned long long)pk16[rr + 4][hc - 1]
       | ((unsigned long long)pk16[rr + 4][hc] << 16)
       | ((unsigned long long)pk16[rr + 4][hc + 1] << 32)) >> 12;
    const unsigned C = (unsigned)(Wc >> 4);        // bit j = tile col 16cx+j

    static_for<9>([&](auto DY) {
        constexpr int dyi = DY.value;              // halo row = rr + dyi
        constexpr int dy = dyi - 4;
        const unsigned long long W = (dyi == 4) ? Wc :
            (((unsigned long long)pk16[rr + dyi][hc - 1]
            | ((unsigned long long)pk16[rr + dyi][hc] << 16)
            | ((unsigned long long)pk16[rr + dyi][hc + 1] << 32)) >> 12);
        static_for<9>([&](auto DX) {
            constexpr int dx = DX.value - 4;
            if constexpr (!(dx == 0 && dy == 0)) {
                constexpr int rk = rank_of(dy * dy + dx * dx);
                const unsigned S = (unsigned)(W >> (4 + dx));
                acc[rk] |= S ^ C;                  // bits >=16 garbage; unread
            }
        });
    });

    // Resolve ascending distance into 4 bitplanes (first-found = min d2).
    unsigned found = 0, p0 = 0, p1 = 0, p2 = 0, p3 = 0;
    static_for<14>([&](auto RI) {
        constexpr int r = RI.value + 1;
        const unsigned nw = acc[r] & ~found;
        found |= acc[r];
        if constexpr (r & 1) p0 |= nw;
        if constexpr (r & 2) p1 |= nw;
        if constexpr (r & 4) p2 |= nw;
        if constexpr (r & 8) p3 |= nw;
    });

    // fw bytes for this chunk (one 16B LDS read).
    const uint4 fvw = *(const uint4*)&fwt[rr][cx * 16];
    const unsigned long long fv0 =
        (unsigned long long)fvw.x | ((unsigned long long)fvw.y << 32);
    const unsigned long long fv1 =
        (unsigned long long)fvw.z | ((unsigned long long)fvw.w << 32);

    unsigned long long obl = 0, obh = 0;
    unsigned long long cq0 = 0, cq1 = 0;
    static_for<2>([&](auto J) {
        constexpr int j = J.value;
        const unsigned long long f = j ? fv1 : fv0;
        const unsigned c0 = (p0 >> (8 * j)) & 0xff;
        const unsigned c1 = (p1 >> (8 * j)) & 0xff;
        const unsigned c2 = (p2 >> (8 * j)) & 0xff;
        const unsigned c3 = (p3 >> (8 * j)) & 0xff;
        const unsigned long long cls = spread8(c0) | (spread8(c1) << 1)
                                     | (spread8(c2) << 2) | (spread8(c3) << 3);
        const unsigned long long cq = (f << 4) | cls;   // fv<=5, no overflow
        if constexpr (j == 0) cq0 = cq; else cq1 = cq;
        static_for<8>([&](auto B) {
            constexpr int b = B.value;
            const unsigned code = (unsigned)((cq >> (8 * b)) & 0xff);
            const unsigned long long bit = 1ull << (code & 63);
            const bool ishi = (code & 64) != 0;
            obl |= ishi ? 0ull : bit;
            obh |= ishi ? bit : 0ull;
        });
    });
    const int gchunk = (ty0 + rr) * HPR + bx * (TW / 16) + cx;
    code16[gchunk] = make_ulonglong2(cq0, cq1);

    // Wave OR-reduce -> LDS -> single block slot pair (no atomics anywhere).
#pragma unroll
    for (int s = 32; s > 0; s >>= 1) {
        obl |= __shfl_xor(obl, s);
        obh |= __shfl_xor(obh, s);
    }
    const int wid = threadIdx.x >> 6, lane = threadIdx.x & 63;
    if (lane == 0) { swl[wid] = obl; swh[wid] = obh; }
    __syncthreads();
    if (threadIdx.x < 64) {
        unsigned long long l2 = (threadIdx.x < 16) ? swl[threadIdx.x] : 0ull;
        unsigned long long h2 = (threadIdx.x < 16) ? swh[threadIdx.x] : 0ull;
#pragma unroll
        for (int s = 8; s > 0; s >>= 1) {
            l2 |= __shfl_xor(l2, s);
            h2 |= __shfl_xor(h2, s);
        }
        if (threadIdx.x == 0) {
            obs_blk[blockIdx.x * 2]     = l2;
            obs_blk[blockIdx.x * 2 + 1] = h2;
        }
    }
}

// Pass C: OR-reduce 256 per-block obs slots (4 KB), build 96-entry table,
// then 16-px-per-thread LDS-table lookup.
__global__ __launch_bounds__(256) void k_out(const ulonglong2* __restrict__ code16,
                                             const unsigned long long* __restrict__ obs_blk,
                                             float* __restrict__ out) {
    __shared__ float tab[96];
    __shared__ float smn[4], smx[4];
    __shared__ unsigned long long slo[4], shi[4];

    const int tid = threadIdx.x;

    // Preamble: global obs = OR of all 256 block slots (one pair per thread).
    unsigned long long lo, hi;
    {
        const ulonglong2 s = ((const ulonglong2*)obs_blk)[tid];
        lo = s.x;
        hi = s.y;
#pragma unroll
        for (int s2 = 32; s2 > 0; s2 >>= 1) {
            lo |= __shfl_xor(lo, s2);
            hi |= __shfl_xor(hi, s2);
        }
        if ((tid & 63) == 0) { slo[tid >> 6] = lo; shi[tid >> 6] = hi; }
        __syncthreads();
        lo = slo[0] | slo[1] | slo[2] | slo[3];
        hi = shi[0] | shi[1] | shi[2] | shi[3];
    }

    float v = 0.f;
    bool present = false;
    if (tid < 96) {
        const int r = tid & 15;
        const float contour = (r >= 1 && r <= 14) ? 1.f / sqrtf((float)D2S[r]) : 0.f;
        const float t0 = (float)(tid >> 4) + contour;
        v = t0 * t0;
        present = (tid < 64) ? ((lo >> tid) & 1) : ((hi >> (tid - 64)) & 1);
    }
    float mnv = present ? v : INFINITY;
    float mxv = present ? v : -INFINITY;
#pragma unroll
    for (int s = 32; s > 0; s >>= 1) {
        mnv = fminf(mnv, __shfl_xor(mnv, s));
        mxv = fmaxf(mxv, __shfl_xor(mxv, s));
    }
    if ((tid & 63) == 0) { smn[tid >> 6] = mnv; smx[tid >> 6] = mxv; }
    __syncthreads();
    const float mn = fminf(fminf(smn[0], smn[1]), fminf(smn[2], smn[3]));
    const float mx = fmaxf(fmaxf(smx[0], smx[1]), fmaxf(smx[2], smx[3]));
    const float inv = 1.f / (mx - mn + 1e-10f);
    if (tid < 96) tab[tid] = (tid >= 16) ? (v - mn) * inv : 0.f;  // fv==0 -> 0
    __syncthreads();

    // 16 px per thread: one ulonglong2 of codes -> 4 float4 stores.
    const int t = blockIdx.x * 256 + tid;
    const ulonglong2 cq = code16[t];
    float4 v0, v1, v2, v3;
    v0.x = tab[(cq.x >> 0) & 0xff];  v0.y = tab[(cq.x >> 8) & 0xff];
    v0.z = tab[(cq.x >> 16) & 0xff]; v0.w = tab[(cq.x >> 24) & 0xff];
    v1.x = tab[(cq.x >> 32) & 0xff]; v1.y = tab[(cq.x >> 40) & 0xff];
    v1.z = tab[(cq.x >> 48) & 0xff]; v1.w = tab[(cq.x >> 56) & 0xff];
    v2.x = tab[(cq.y >> 0) & 0xff];  v2.y = tab[(cq.y >> 8) & 0xff];
    v2.z = tab[(cq.y >> 16) & 0xff]; v2.w = tab[(cq.y >> 24) & 0xff];
    v3.x = tab[(cq.y >> 32) & 0xff]; v3.y = tab[(cq.y >> 40) & 0xff];
    v3.z = tab[(cq.y >> 48) & 0xff]; v3.w = tab[(cq.y >> 56) & 0xff];
    const int ob = t * 16;
    *(float4*)(out + ob + 0)  = v0;
    *(float4*)(out + ob + 4)  = v1;
    *(float4*)(out + ob + 8)  = v2;
    *(float4*)(out + ob + 12) = v3;
}

extern "C" void kernel_launch(void* const* d_in, const int* in_sizes, int n_in,
                              void* d_out, int out_size, void* d_ws, size_t ws_size,
                              hipStream_t stream) {
    const float* target = (const float*)d_in[0];
    float* out = (float*)d_out;

    // ws layout (16B-aligned): code (NPIX bytes) | obs_blk (256*16 B)
    unsigned char* code = (unsigned char*)d_ws;
    unsigned long long* obs_blk = (unsigned long long*)(code + NPIX);

    k_packdist<<<GX * GY, 1024, 0, stream>>>(
        target, (ulonglong2*)code, obs_blk);

    k_out<<<NPIX / 16 / 256, 256, 0, stream>>>(
        (const ulonglong2*)code, obs_blk, out);
}

// Round 15
// 37.338 us; speedup vs baseline: 1.2118x; 1.1624x over previous
//
#include <hip/hip_runtime.h>
#include <math.h>
#include <utility>

static constexpr int HH = 2048;
static constexpr int WW = 2048;
static constexpr int NPIX = HH * WW;
static constexpr int WPR32 = WW / 32;      // 64 packed u32 words per row
static constexpr int HPR = WW / 16;        // 128 u16 chunks per row
static constexpr int DBLK = HH / 2;        // 1024 dist blocks (2 rows each)

// Compile-time-forced loop unrolling (keeps acc[] in registers).
template <typename F, int... Is>
__device__ __forceinline__ void sf_impl(F&& f, std::integer_sequence<int, Is...>) {
    (f(std::integral_constant<int, Is>{}), ...);
}
template <int N, typename F>
__device__ __forceinline__ void static_for(F&& f) {
    sf_impl(f, std::make_integer_sequence<int, N>{});
}

// Rank of squared distance among the 14 distinct d2 values in the 9x9
// neighborhood (ascending). 0 = "no differing neighbor".
__host__ __device__ constexpr int rank_of(int d2) {
    switch (d2) {
        case 1:  return 1;  case 2:  return 2;  case 4:  return 3;
        case 5:  return 4;  case 8:  return 5;  case 9:  return 6;
        case 10: return 7;  case 13: return 8;  case 16: return 9;
        case 17: return 10; case 18: return 11; case 20: return 12;
        case 25: return 13; case 32: return 14;
    }
    return 0;
}

__device__ const int D2S[16] = {0, 1, 2, 4, 5, 8, 9, 10, 13, 16, 17, 18, 20, 25, 32, 0};

// Spread the 8 bits of b into the 8 bytes of a u64 (byte i = (b>>i)&1).
__device__ __forceinline__ unsigned long long spread8(unsigned int b) {
    unsigned long long t = (unsigned long long)b * 0x0101010101010101ull;
    t &= 0x8040201008040201ull;
    return ((t + 0x7f7f7f7f7f7f7f7full) >> 7) & 0x0101010101010101ull;
}

// Pass A: fw byte map (sum of 5 binary masks) + bit-packed combined mask.
// (R11 verbatim — measured near HBM floor.)
__global__ __launch_bounds__(256) void k_pack(const float* __restrict__ t,
                                              unsigned char* __restrict__ fw,
                                              unsigned char* __restrict__ pk) {
    const int tid = blockIdx.x * 256 + threadIdx.x;
    const int base = tid * 8;
    unsigned long long fwq = 0;
    unsigned int bits = 0;
#pragma unroll
    for (int h = 0; h < 2; ++h) {
        const int o = base + 4 * h;
        float4 a = *(const float4*)(t + 0 * NPIX + o);
        float4 b = *(const float4*)(t + 1 * NPIX + o);
        float4 c = *(const float4*)(t + 2 * NPIX + o);
        float4 d = *(const float4*)(t + 3 * NPIX + o);
        float4 e = *(const float4*)(t + 4 * NPIX + o);
        const float s0 = a.x + b.x + c.x + d.x + e.x;
        const float s1 = a.y + b.y + c.y + d.y + e.y;
        const float s2 = a.z + b.z + c.z + d.z + e.z;
        const float s3 = a.w + b.w + c.w + d.w + e.w;
        const int j = 4 * h;
        fwq |= ((unsigned long long)(int)s0) << (8 * j);
        fwq |= ((unsigned long long)(int)s1) << (8 * (j + 1));
        fwq |= ((unsigned long long)(int)s2) << (8 * (j + 2));
        fwq |= ((unsigned long long)(int)s3) << (8 * (j + 3));
        bits |= (s0 > 0.f ? 1u : 0u) << j;
        bits |= (s1 > 0.f ? 1u : 0u) << (j + 1);
        bits |= (s2 > 0.f ? 1u : 0u) << (j + 2);
        bits |= (s3 > 0.f ? 1u : 0u) << (j + 3);
    }
    *(unsigned long long*)(fw + base) = fwq;
    pk[tid] = (unsigned char)bits;
}

// Pass B: bit-parallel min-squared-distance classification, u16 grain.
// R15 vs R11 (single structural variable): 1024 blocks x 256 threads
// (block = 2 image rows; 10-row halo tile = 2.5 KB LDS; 4 blocks/CU,
// fine dispatch grain, small barrier scope) instead of 256 x 1024.
// Window math, epilogue, obs handling identical to validated R11.
__global__ __launch_bounds__(256, 4) void k_dist(const unsigned* __restrict__ pk32,
                                                 const ulonglong2* __restrict__ fw16,
                                                 ulonglong2* __restrict__ code16,
                                                 unsigned long long* __restrict__ obs_blk) {
    __shared__ unsigned tile[10][WPR32];   // 10 rows x 64 u32 = 2.56 KB
    __shared__ unsigned long long swl[4], swh[4];

    const int y0 = blockIdx.x * 2;
    // Halo load: rows clamp(y0-4 .. y0+5), full width (640 u32).
#pragma unroll
    for (int k = 0; k < 3; ++k) {
        const int i = threadIdx.x + k * 256;
        if (i < 640) {
            const int r = i >> 6;
            const int c = i & 63;
            const int gy = min(max(y0 - 4 + r, 0), HH - 1);
            tile[r][c] = pk32[gy * WPR32 + c];
        }
    }

    const int ty = threadIdx.x >> 7;        // 0..1 row within block
    const int hx = threadIdx.x & 127;       // u16 chunk within row
    const int wx = hx >> 1;                 // owning u32 word
    const int h = hx & 1;                   // low/high half
    const int chunk = (y0 + ty) * HPR + hx; // global chunk index

    // Prefetch this chunk's 16 fv bytes (consumed only in the epilogue).
    const ulonglong2 fv2 = fw16[chunk];

    __syncthreads();

    unsigned acc[15];
    static_for<15>([&](auto I) { acc[I.value] = 0u; });

    // Center-row window (tile row ty+4), validated R11 construction.
    const unsigned Cw = tile[ty + 4][wx];
    const unsigned C = h ? (Cw >> 16) : (Cw & 0xffffu);

    static_for<9>([&](auto DY) {
        constexpr int dyi = DY.value;       // tile row = ty + dyi
        constexpr int dy = dyi - 4;
        const int r = ty + dyi;
        const unsigned M = tile[r][wx];
        unsigned long long W;
        if (h == 0) {
            // bits [-4, 20) of this chunk: P[28..31] ++ M[0..19]
            const unsigned P = (wx > 0) ? tile[r][wx - 1] : ((M & 1u) ? ~0u : 0u);
            W = ((unsigned long long)M << 4) | (P >> 28);
        } else {
            // bits [-4, 20) rel. to bit16: M[12..31] ++ N[0..3]
            const unsigned N = (wx < WPR32 - 1) ? tile[r][wx + 1]
                                                : ((M >> 31) ? ~0u : 0u);
            W = ((unsigned long long)N << 20) | (M >> 12);
        }
        static_for<9>([&](auto DX) {
            constexpr int dx = DX.value - 4;
            if constexpr (!(dx == 0 && dy == 0)) {
                constexpr int rk = rank_of(dy * dy + dx * dx);
                const unsigned S = (unsigned)(W >> (4 + dx));
                acc[rk] |= S ^ C;               // bits >=16 garbage; never read
            }
        });
    });

    // Resolve ascending distance into 4 bitplanes (first-found = min d2).
    unsigned found = 0, p0 = 0, p1 = 0, p2 = 0, p3 = 0;
    static_for<14>([&](auto RI) {
        constexpr int r = RI.value + 1;
        const unsigned nw = acc[r] & ~found;
        found |= acc[r];
        if constexpr (r & 1) p0 |= nw;
        if constexpr (r & 2) p1 |= nw;
        if constexpr (r & 4) p2 |= nw;
        if constexpr (r & 8) p3 |= nw;
    });

    // Epilogue: assemble 16 code bytes (code = fv<<4 | cls); track observed.
    unsigned long long obl = 0, obh = 0;
    unsigned long long cq0 = 0, cq1 = 0;
    static_for<2>([&](auto J) {
        constexpr int j = J.value;
        const unsigned long long f = j ? fv2.y : fv2.x;
        const unsigned c0 = (p0 >> (8 * j)) & 0xff;
        const unsigned c1 = (p1 >> (8 * j)) & 0xff;
        const unsigned c2 = (p2 >> (8 * j)) & 0xff;
        const unsigned c3 = (p3 >> (8 * j)) & 0xff;
        const unsigned long long cls = spread8(c0) | (spread8(c1) << 1)
                                     | (spread8(c2) << 2) | (spread8(c3) << 3);
        const unsigned long long cq = (f << 4) | cls;   // fv<=5, no overflow
        if constexpr (j == 0) cq0 = cq; else cq1 = cq;
        static_for<8>([&](auto B) {
            constexpr int b = B.value;
            const unsigned code = (unsigned)((cq >> (8 * b)) & 0xff);
            const unsigned long long bit = 1ull << (code & 63);
            const bool ishi = (code & 64) != 0;
            obl |= ishi ? 0ull : bit;
            obh |= ishi ? bit : 0ull;
        });
    });
    code16[chunk] = make_ulonglong2(cq0, cq1);

    // Wave OR-reduce -> LDS -> single block slot pair (no atomics anywhere).
#pragma unroll
    for (int s = 32; s > 0; s >>= 1) {
        obl |= __shfl_xor(obl, s);
        obh |= __shfl_xor(obh, s);
    }
    const int wid = threadIdx.x >> 6, lane = threadIdx.x & 63;
    if (lane == 0) { swl[wid] = obl; swh[wid] = obh; }
    __syncthreads();
    if (threadIdx.x == 0) {
        obs_blk[blockIdx.x * 2]     = swl[0] | swl[1] | swl[2] | swl[3];
        obs_blk[blockIdx.x * 2 + 1] = swh[0] | swh[1] | swh[2] | swh[3];
    }
}

// Pass C: OR-reduce 1024 per-block obs slots (16 KB), build 96-entry table,
// then 16-px-per-thread LDS-table lookup. (R11 verbatim except 4 slots/thr.)
__global__ __launch_bounds__(256) void k_out(const ulonglong2* __restrict__ code16,
                                             const unsigned long long* __restrict__ obs_blk,
                                             float* __restrict__ out) {
    __shared__ float tab[96];
    __shared__ float smn[4], smx[4];
    __shared__ unsigned long long slo[4], shi[4];

    const int tid = threadIdx.x;

    // Preamble: global obs = OR of all 1024 block slots (4 pairs per thread).
    unsigned long long lo = 0, hi = 0;
    {
        const ulonglong2* sl2 = (const ulonglong2*)obs_blk;
#pragma unroll
        for (int i = 0; i < 4; ++i) {
            const ulonglong2 s = sl2[tid * 4 + i];
            lo |= s.x;
            hi |= s.y;
        }
#pragma unroll
        for (int s2 = 32; s2 > 0; s2 >>= 1) {
            lo |= __shfl_xor(lo, s2);
            hi |= __shfl_xor(hi, s2);
        }
        if ((tid & 63) == 0) { slo[tid >> 6] = lo; shi[tid >> 6] = hi; }
        __syncthreads();
        lo = slo[0] | slo[1] | slo[2] | slo[3];
        hi = shi[0] | shi[1] | shi[2] | shi[3];
    }

    float v = 0.f;
    bool present = false;
    if (tid < 96) {
        const int r = tid & 15;
        const float contour = (r >= 1 && r <= 14) ? 1.f / sqrtf((float)D2S[r]) : 0.f;
        const float t0 = (float)(tid >> 4) + contour;
        v = t0 * t0;
        present = (tid < 64) ? ((lo >> tid) & 1) : ((hi >> (tid - 64)) & 1);
    }
    float mnv = present ? v : INFINITY;
    float mxv = present ? v : -INFINITY;
#pragma unroll
    for (int s = 32; s > 0; s >>= 1) {
        mnv = fminf(mnv, __shfl_xor(mnv, s));
        mxv = fmaxf(mxv, __shfl_xor(mxv, s));
    }
    if ((tid & 63) == 0) { smn[tid >> 6] = mnv; smx[tid >> 6] = mxv; }
    __syncthreads();
    const float mn = fminf(fminf(smn[0], smn[1]), fminf(smn[2], smn[3]));
    const float mx = fmaxf(fmaxf(smx[0], smx[1]), fmaxf(smx[2], smx[3]));
    const float inv = 1.f / (mx - mn + 1e-10f);
    if (tid < 96) tab[tid] = (tid >= 16) ? (v - mn) * inv : 0.f;  // fv==0 -> 0
    __syncthreads();

    // 16 px per thread: one ulonglong2 of codes -> 4 float4 stores.
    const int t = blockIdx.x * 256 + tid;
    const ulonglong2 cq = code16[t];
    float4 v0, v1, v2, v3;
    v0.x = tab[(cq.x >> 0) & 0xff];  v0.y = tab[(cq.x >> 8) & 0xff];
    v0.z = tab[(cq.x >> 16) & 0xff]; v0.w = tab[(cq.x >> 24) & 0xff];
    v1.x = tab[(cq.x >> 32) & 0xff]; v1.y = tab[(cq.x >> 40) & 0xff];
    v1.z = tab[(cq.x >> 48) & 0xff]; v1.w = tab[(cq.x >> 56) & 0xff];
    v2.x = tab[(cq.y >> 0) & 0xff];  v2.y = tab[(cq.y >> 8) & 0xff];
    v2.z = tab[(cq.y >> 16) & 0xff]; v2.w = tab[(cq.y >> 24) & 0xff];
    v3.x = tab[(cq.y >> 32) & 0xff]; v3.y = tab[(cq.y >> 40) & 0xff];
    v3.z = tab[(cq.y >> 48) & 0xff]; v3.w = tab[(cq.y >> 56) & 0xff];
    const int ob = t * 16;
    *(float4*)(out + ob + 0)  = v0;
    *(float4*)(out + ob + 4)  = v1;
    *(float4*)(out + ob + 8)  = v2;
    *(float4*)(out + ob + 12) = v3;
}

extern "C" void kernel_launch(void* const* d_in, const int* in_sizes, int n_in,
                              void* d_out, int out_size, void* d_ws, size_t ws_size,
                              hipStream_t stream) {
    const float* target = (const float*)d_in[0];
    float* out = (float*)d_out;

    // ws layout (16B-aligned sections): fw | packed | code | obs_blk
    unsigned char* fw = (unsigned char*)d_ws;                         // NPIX bytes
    unsigned char* pk = fw + NPIX;                                    // NPIX/8 bytes
    unsigned char* code = pk + NPIX / 8;                              // NPIX bytes
    unsigned long long* obs_blk = (unsigned long long*)(code + NPIX); // 1024*16 B

    k_pack<<<NPIX / 8 / 256, 256, 0, stream>>>(target, fw, pk);

    k_dist<<<DBLK, 256, 0, stream>>>(
        (const unsigned*)pk, (const ulonglong2*)fw,
        (ulonglong2*)code, obs_blk);

    k_out<<<NPIX / 16 / 256, 256, 0, stream>>>(
        (const ulonglong2*)code, obs_blk, out);
}